// Round 13
// baseline (88.747 us; speedup 1.0000x reference)
//
#include <hip/hip_runtime.h>
#include <hip/hip_bf16.h>

// Chamfer distance, B=4, N=M=8192, D=3, fp32.
// R12: ONE self-finalizing kernel (MSPLIT=1). Each block owns 128 query cols
// and loops over ALL 8192 targets of its batch (8 LDS stages x 1024), so its
// per-query minima are FINAL -> block partial sum -> one atomicAdd(ws).
// Finalization without a second graph node: ws is re-poisoned to 0xAA every
// launch, so a uint counter in ws starts at 0xAAAAAAAA deterministically;
// the 512th arriving block (release/acquire fenced) writes out[0].
// float accumulator's poison start = -3.03e-13 (negligible vs 9.3e-4 thr).
// Main loop per iter (unchanged, verified absmax 0.0 since R7):
//   2 ds_read_b128 + [2 VGPR-dst MFMA + 2 s_nop7] + 16 v_min3.
// Payload k0..15 (target A x query B): -2h.h | -2l.h | -2h.l | qn.1 | 1.tn | 0
// Graph: 1 kernel node, 0 memsets, ws use = 8 bytes.

typedef __attribute__((ext_vector_type(8)))  short short8;
typedef __attribute__((ext_vector_type(16))) float f32x16;

#define BATCH 4
#define NPTS 8192
#define TOTALQ (BATCH * NPTS)   // 32768
#define BLK 256
#define BCOLS 128               // query cols per block (4 waves x 32)
#define NBLK ((TOTALQ / BCOLS) * 2)  // 512 blocks total
#define MC 1024                 // targets per LDS stage
#define NSTAGE (NPTS / MC)      // 8 stages
#define MT_PER (MC / 32)        // 32 target tiles per stage
#define POISON_U 0xAAAAAAAAu

__device__ __forceinline__ unsigned short f2bf(float f) {  // RTN-even
    unsigned int u = __float_as_uint(f);
    u += 0x7FFFu + ((u >> 16) & 1u);
    return (unsigned short)(u >> 16);
}
__device__ __forceinline__ float bf2f(unsigned short h) {
    return __uint_as_float(((unsigned int)h) << 16);
}
__device__ __forceinline__ unsigned int pk2(unsigned short a, unsigned short b) {
    return (unsigned int)a | ((unsigned int)b << 16);
}

struct Payload {
    unsigned short hx, hy, hz, lx, ly, lz, n1, n2, n3;
};
__device__ __forceinline__ Payload split_point(float x, float y, float z) {
    Payload P;
    P.hx = f2bf(x);  P.hy = f2bf(y);  P.hz = f2bf(z);
    P.lx = f2bf(x - bf2f(P.hx));
    P.ly = f2bf(y - bf2f(P.hy));
    P.lz = f2bf(z - bf2f(P.hz));
    float nrm = fmaf(z, z, fmaf(y, y, x * x));
    P.n1 = f2bf(nrm);
    float r1 = nrm - bf2f(P.n1);
    P.n2 = f2bf(r1);
    P.n3 = f2bf(r1 - bf2f(P.n2));
    return P;
}

__global__ __launch_bounds__(BLK) void chamfer_mono_kernel(
        const float* __restrict__ pred, const float* __restrict__ target,
        float* __restrict__ wsacc, unsigned int* __restrict__ wscnt,
        float* __restrict__ out)
{
    const int dir = blockIdx.y;
    const float* __restrict__ Q  = dir ? target : pred;   // outputs (B cols)
    const float* __restrict__ Tg = dir ? pred : target;   // min-over (A rows, LDS)

    const int nch = blockIdx.x;            // 0..255 (128-query chunk)
    const int b   = nch >> 6;              // batch (64 chunks per batch)
    const int w    = threadIdx.x >> 6;
    const int lane = threadIdx.x & 63;
    const int c = lane & 31;               // row (A) / col (B) within tile
    const int g = lane >> 5;               // k-half
    const unsigned short ONE = 0x3F80;

    __shared__ uint4 ldsb[2][MC];          // 32 KB (two k-halves)
    __shared__ float bsum[4];

    // ---- B fragment (queries): in-register pack, col = colstart + c ----
    const int colstart = nch * BCOLS + w * 32;
    short8 bq;
    {
        int r = colstart + c;
        float x = Q[3 * r], y = Q[3 * r + 1], z = Q[3 * r + 2];
        Payload P = split_point(x, y, z);
        unsigned short ax = f2bf(-2.f * bf2f(P.hx)),
                       ay = f2bf(-2.f * bf2f(P.hy)),
                       az = f2bf(-2.f * bf2f(P.hz));
        unsigned short cx = f2bf(-2.f * bf2f(P.lx)),
                       cy = f2bf(-2.f * bf2f(P.ly)),
                       cz = f2bf(-2.f * bf2f(P.lz));
        uint4 h0 = { pk2(ax, ay), pk2(az, cx), pk2(cy, cz), pk2(ax, ay) };
        uint4 h1 = { pk2(az, P.n1), pk2(P.n2, P.n3), pk2(ONE, ONE), pk2(ONE, 0) };
        uint4 sel = g ? h1 : h0;
        bq = *(short8*)&sel;
    }

    f32x16 acc;
    #pragma unroll
    for (int r = 0; r < 16; ++r) acc[r] = 3.4e38f;
    f32x16 vzero;
    #pragma unroll
    for (int r = 0; r < 16; ++r) vzero[r] = 0.0f;

    const ushort* ldsu = (const ushort*)&ldsb[g][0];   // this lane's k-half
    const size_t tbase = (size_t)b * NPTS;

    for (int st = 0; st < NSTAGE; ++st) {
        __syncthreads();                   // protect prior stage's reads
        // ---- stage MC target points: raw read -> payload -> LDS ----
        #pragma unroll
        for (int j = 0; j < MC / BLK; ++j) {
            int p = j * BLK + threadIdx.x;
            size_t gp = tbase + (size_t)st * MC + p;
            float x = Tg[3 * gp], y = Tg[3 * gp + 1], z = Tg[3 * gp + 2];
            Payload P = split_point(x, y, z);
            ldsb[0][p] = (uint4){ pk2(P.hx, P.hy), pk2(P.hz, P.hx),
                                  pk2(P.hy, P.hz), pk2(P.lx, P.ly) };
            ldsb[1][p] = (uint4){ pk2(P.lz, ONE), pk2(ONE, ONE),
                                  pk2(P.n1, P.n2), pk2(P.n3, 0) };
        }
        __syncthreads();

        // ---- 16 iters: 2 ds_read_b128 + 2 MFMA (VGPR dst) + 16 min3 ----
        for (int mt = 0; mt < MT_PER; mt += 2) {
            short8 at0 = *(const short8*)(ldsu + (mt * 32 + c) * 8);
            short8 at1 = *(const short8*)(ldsu + ((mt + 1) * 32 + c) * 8);
            f32x16 d0, d1;
            asm("v_mfma_f32_32x32x16_bf16 %0, %2, %4, %5\n\t"
                "v_mfma_f32_32x32x16_bf16 %1, %3, %4, %5\n\t"
                "s_nop 7\n\t"
                "s_nop 7"
                : "=&v"(d0), "=&v"(d1)
                : "v"(at0), "v"(at1), "v"(bq), "v"(vzero));
            #pragma unroll
            for (int r = 0; r < 16; ++r)
                acc[r] = fminf(fminf(acc[r], d0[r]), d1[r]);   // v_min3
        }
    }

    // ---- epilogue: per-query FINAL min (16 regs in-lane + g-half shfl) ----
    float m0 = fminf(fminf(acc[0],  acc[1]),  fminf(acc[2],  acc[3]));
    float m1 = fminf(fminf(acc[4],  acc[5]),  fminf(acc[6],  acc[7]));
    float m2 = fminf(fminf(acc[8],  acc[9]),  fminf(acc[10], acc[11]));
    float m3 = fminf(fminf(acc[12], acc[13]), fminf(acc[14], acc[15]));
    float m  = fminf(fminf(m0, m1), fminf(m2, m3));
    m = fminf(m, __shfl_xor(m, 32, 64));

    // ---- block partial sum of means ----
    float v = (g == 0) ? m * (1.0f / (float)TOTALQ) : 0.0f;
    #pragma unroll
    for (int off = 32; off > 0; off >>= 1)
        v += __shfl_down(v, off, 64);
    if (lane == 0) bsum[w] = v;
    __syncthreads();

    // ---- device-level finalization via poison-initialized counter ----
    if (threadIdx.x == 0) {
        float s = (bsum[0] + bsum[1]) + (bsum[2] + bsum[3]);
        atomicAdd(wsacc, s);               // device-scope (m20)
        __threadfence();                   // release: my add visible
        unsigned int old = atomicAdd(wscnt, 1u);   // starts at 0xAAAAAAAA
        if (old == POISON_U + (NBLK - 1)) {
            __threadfence();               // acquire
            out[0] = __hip_atomic_load(wsacc, __ATOMIC_RELAXED,
                                       __HIP_MEMORY_SCOPE_AGENT);
        }
    }
}

extern "C" void kernel_launch(void* const* d_in, const int* in_sizes, int n_in,
                              void* d_out, int out_size, void* d_ws, size_t ws_size,
                              hipStream_t stream) {
    const float*  pred   = (const float*)d_in[0];
    const float*  target = (const float*)d_in[1];
    float*        out    = (float*)d_out;
    float*        wsacc  = (float*)d_ws;                 // poison -3e-13 ~ 0
    unsigned int* wscnt  = (unsigned int*)d_ws + 1;      // poison 0xAAAAAAAA

    dim3 grid(TOTALQ / BCOLS, 2);          // 256 x 2 = 512 blocks
    hipLaunchKernelGGL(chamfer_mono_kernel, grid, dim3(BLK), 0, stream,
                       pred, target, wsacc, wscnt, out);
}

// Round 14
// 77.699 us; speedup vs baseline: 1.1422x; 1.1422x over previous
//
#include <hip/hip_runtime.h>
#include <hip/hip_bf16.h>

// Chamfer distance, B=4, N=M=8192, D=3, fp32.
// R13: R12's mono regressed (2 waves/SIMD, no prefetch -> ds latency exposed,
// Occ 13%/VALU 29%). Revert to R11 (best: 77.6 us total) + ONE change:
// software-prefetch the next mt-pair's ds_read_b128 one iteration ahead
// ((mt+2)&31 keeps addresses valid; last-iter prefetch discarded), so the
// lgkmcnt wait before the MFMA blob covers loads issued ~300 cyc earlier.
// Geometry (R11): 1024 blocks (64 nch x 8 ms x 2 dir), 4 waves, WNT=4,
// MC=1024 single LDS stage. Payload & asm blob unchanged (absmax 0.0 R7-R13).
//   payload k0..15 (target A x query B): -2h.h | -2l.h | -2h.l | qn.1 | 1.tn
// C/D 32x32 (m74/m101): col=lane&31, row=(reg&3)+8*(reg>>2)+4*(lane>>5).

typedef __attribute__((ext_vector_type(8)))  short short8;
typedef __attribute__((ext_vector_type(16))) float f32x16;

#define BATCH 4
#define NPTS 8192
#define TOTALQ (BATCH * NPTS)   // 32768
#define BLK 256
#define WNT 4                   // 32-col B tiles per wave -> 128 queries/wave
#define BCOLS 512               // query cols per block (4 waves)
#define MSPLIT 8                // target slices per batch
#define MC (NPTS / MSPLIT)      // 1024 targets per block, single LDS stage
#define MT_PER (MC / 32)        // 32 target tiles

__device__ __forceinline__ unsigned short f2bf(float f) {  // RTN-even
    unsigned int u = __float_as_uint(f);
    u += 0x7FFFu + ((u >> 16) & 1u);
    return (unsigned short)(u >> 16);
}
__device__ __forceinline__ float bf2f(unsigned short h) {
    return __uint_as_float(((unsigned int)h) << 16);
}
__device__ __forceinline__ unsigned int pk2(unsigned short a, unsigned short b) {
    return (unsigned int)a | ((unsigned int)b << 16);
}

struct Payload {
    unsigned short hx, hy, hz, lx, ly, lz, n1, n2, n3;
};
__device__ __forceinline__ Payload split_point(float x, float y, float z) {
    Payload P;
    P.hx = f2bf(x);  P.hy = f2bf(y);  P.hz = f2bf(z);
    P.lx = f2bf(x - bf2f(P.hx));
    P.ly = f2bf(y - bf2f(P.hy));
    P.lz = f2bf(z - bf2f(P.hz));
    float nrm = fmaf(z, z, fmaf(y, y, x * x));
    P.n1 = f2bf(nrm);
    float r1 = nrm - bf2f(P.n1);
    P.n2 = f2bf(r1);
    P.n3 = f2bf(r1 - bf2f(P.n2));
    return P;
}

__global__ __launch_bounds__(BLK) void chamfer_mega_kernel(
        const float* __restrict__ pred, const float* __restrict__ target,
        float* __restrict__ part, float* __restrict__ out)
{
    const int dir = blockIdx.z;
    const float* __restrict__ Q  = dir ? target : pred;   // outputs (B cols)
    const float* __restrict__ Tg = dir ? pred : target;   // min-over (A rows, LDS)

    const int nch = blockIdx.x;            // 0..63 (512-query-col chunk)
    const int b   = nch >> 4;              // batch (16 chunks per batch)
    const int ms  = blockIdx.y;            // 0..7 target slice
    const int w    = threadIdx.x >> 6;
    const int lane = threadIdx.x & 63;
    const int c = lane & 31;               // row (A) / col (B) within tile
    const int g = lane >> 5;               // k-half
    const unsigned short ONE = 0x3F80;

    if (blockIdx.x == 0 && blockIdx.y == 0 && blockIdx.z == 0 &&
        threadIdx.x == 0) out[0] = 0.0f;   // consumed after kernel boundary

    __shared__ uint4 ldsb[2][MC];          // 32 KB (two k-halves)

    // ---- stage MC target points: raw read -> payload -> LDS (A operand) ----
    #pragma unroll
    for (int j = 0; j < MC / BLK; ++j) {
        int p = j * BLK + threadIdx.x;
        size_t gp = (size_t)b * NPTS + (size_t)ms * MC + p;
        float x = Tg[3 * gp], y = Tg[3 * gp + 1], z = Tg[3 * gp + 2];
        Payload P = split_point(x, y, z);
        ldsb[0][p] = (uint4){ pk2(P.hx, P.hy), pk2(P.hz, P.hx),
                              pk2(P.hy, P.hz), pk2(P.lx, P.ly) };
        ldsb[1][p] = (uint4){ pk2(P.lz, ONE), pk2(ONE, ONE),
                              pk2(P.n1, P.n2), pk2(P.n3, 0) };
    }

    // ---- B fragments (queries): in-register pack, col = colstart + nt*32 + c ----
    const int colstart = nch * BCOLS + w * (WNT * 32);
    short8 bq[WNT];
    #pragma unroll
    for (int nt = 0; nt < WNT; ++nt) {
        int r = colstart + nt * 32 + c;
        float x = Q[3 * r], y = Q[3 * r + 1], z = Q[3 * r + 2];
        Payload P = split_point(x, y, z);
        unsigned short ax = f2bf(-2.f * bf2f(P.hx)),
                       ay = f2bf(-2.f * bf2f(P.hy)),
                       az = f2bf(-2.f * bf2f(P.hz));
        unsigned short cx = f2bf(-2.f * bf2f(P.lx)),
                       cy = f2bf(-2.f * bf2f(P.ly)),
                       cz = f2bf(-2.f * bf2f(P.lz));
        uint4 h0 = { pk2(ax, ay), pk2(az, cx), pk2(cy, cz), pk2(ax, ay) };
        uint4 h1 = { pk2(az, P.n1), pk2(P.n2, P.n3), pk2(ONE, ONE), pk2(ONE, 0) };
        uint4 sel = g ? h1 : h0;
        bq[nt] = *(short8*)&sel;
    }

    f32x16 acc[WNT];
    #pragma unroll
    for (int nt = 0; nt < WNT; ++nt)
        #pragma unroll
        for (int r = 0; r < 16; ++r) acc[nt][r] = 3.4e38f;

    f32x16 vzero;
    #pragma unroll
    for (int r = 0; r < 16; ++r) vzero[r] = 0.0f;

    __syncthreads();

    const ushort* ldsu = (const ushort*)&ldsb[g][0];   // this lane's k-half

    // ---- main loop, software-pipelined ds_reads:
    //      consume at0/at1 (loaded LAST iteration), prefetch next pair ----
    short8 at0 = *(const short8*)(ldsu + (0 * 32 + c) * 8);
    short8 at1 = *(const short8*)(ldsu + (1 * 32 + c) * 8);
    #pragma unroll 2
    for (int mt = 0; mt < MT_PER; mt += 2) {
        int mtn = (mt + 2) & (MT_PER - 1);             // always-valid address
        short8 nx0 = *(const short8*)(ldsu + (mtn * 32 + c) * 8);
        short8 nx1 = *(const short8*)(ldsu + ((mtn + 1) * 32 + c) * 8);
        #pragma unroll
        for (int nt = 0; nt < WNT; ++nt) {
            f32x16 d0, d1;
            // A = target tile (LDS), B = query tile (regs); VGPR dst.
            // s_nop pads the MFMA-write -> VALU-read hazard.
            asm("v_mfma_f32_32x32x16_bf16 %0, %2, %4, %5\n\t"
                "v_mfma_f32_32x32x16_bf16 %1, %3, %4, %5\n\t"
                "s_nop 7\n\t"
                "s_nop 7"
                : "=&v"(d0), "=&v"(d1)
                : "v"(at0), "v"(at1), "v"(bq[nt]), "v"(vzero));
            #pragma unroll
            for (int r = 0; r < 16; ++r)
                acc[nt][r] = fminf(fminf(acc[nt][r], d0[r]), d1[r]); // v_min3
        }
        at0 = nx0;  at1 = nx1;
    }

    // ---- epilogue: min over the 16 regs (rows) in-lane + 1 shfl for g ----
    float* rp = part + (size_t)(dir * MSPLIT + ms) * TOTALQ;
    #pragma unroll
    for (int nt = 0; nt < WNT; ++nt) {
        f32x16 v = acc[nt];
        float m0 = fminf(fminf(v[0],  v[1]),  fminf(v[2],  v[3]));
        float m1 = fminf(fminf(v[4],  v[5]),  fminf(v[6],  v[7]));
        float m2 = fminf(fminf(v[8],  v[9]),  fminf(v[10], v[11]));
        float m3 = fminf(fminf(v[12], v[13]), fminf(v[14], v[15]));
        float m  = fminf(fminf(m0, m1), fminf(m2, m3));
        m = fminf(m, __shfl_xor(m, 32, 64));    // fold the two k-half rows
        if (g == 0) rp[colstart + nt * 32 + c] = m;
    }
}

__global__ __launch_bounds__(BLK) void chamfer_reduce_kernel(
        const float* __restrict__ part, float* __restrict__ out)
{
    int gl = blockIdx.x * BLK + threadIdx.x;   // 0..65535
    int dir = gl >> 15, i = gl & (TOTALQ - 1);

    const float* p = part + (size_t)dir * MSPLIT * TOTALQ + i;
    float m = p[0];
    #pragma unroll
    for (int s = 1; s < MSPLIT; ++s)
        m = fminf(m, p[(size_t)s * TOTALQ]);

    float acc = m * (1.0f / (float)TOTALQ);
    #pragma unroll
    for (int off = 32; off > 0; off >>= 1)
        acc += __shfl_down(acc, off, 64);
    __shared__ float wsum[BLK / 64];
    int lane = threadIdx.x & 63, wid = threadIdx.x >> 6;
    if (lane == 0) wsum[wid] = acc;
    __syncthreads();
    if (threadIdx.x == 0) {
        float s = 0.0f;
        #pragma unroll
        for (int wv = 0; wv < BLK / 64; ++wv) s += wsum[wv];
        atomicAdd(out, s);
    }
}

extern "C" void kernel_launch(void* const* d_in, const int* in_sizes, int n_in,
                              void* d_out, int out_size, void* d_ws, size_t ws_size,
                              hipStream_t stream) {
    const float* pred   = (const float*)d_in[0];
    const float* target = (const float*)d_in[1];
    float*       out    = (float*)d_out;
    float*       part   = (float*)d_ws;   // 2 dirs x 8 slices x 32768 = 2 MB

    dim3 grid(TOTALQ / BCOLS, MSPLIT, 2);   // 64 x 8 x 2 = 1024 blocks
    hipLaunchKernelGGL(chamfer_mega_kernel, grid, dim3(BLK), 0, stream,
                       pred, target, part, out);

    hipLaunchKernelGGL(chamfer_reduce_kernel, dim3(2 * TOTALQ / BLK), dim3(BLK),
                       0, stream, (const float*)part, out);
}